// Round 1
// 23357.695 us; speedup vs baseline: 1.0515x; 1.0515x over previous
//
#include <hip/hip_runtime.h>
#include <hip/hip_bf16.h>

// ---------------------------------------------------------------------------
// Decoder: 200-step attention LSTM decoder.
//   prep_kernel : convert/permute weights & KV to bf16, zero state+barrier
//   k1_gemm     : X1pre[t,n,2048] = emb[text] @ Wih1_emb^T + (b_ih1+b_hh1)  (MFMA)
//   loop_kernel : persistent 256-WG kernel, 200 steps, 3 grid barriers/step,
//                 LDS-resident weight slices + KV slices
//   k4_gemm     : out[n,l,:] = [h2|ctx] @ W_out^T + b_out                    (MFMA)
// Workspace requirement: ~93.3 MB.
//
// Barrier v2: the old single-counter barrier serialized 256 contended atomic
// RMWs on one cacheline (~39us/barrier x 600 = ~23ms, the entire runtime).
// New: flag-array barrier (parallel release-stores to 256 distinct lines,
// WG0 detects, single gen release). Flags live in d_out (dead during loop,
// overwritten by k4). Replay-safe: flags are zeroed at loop_kernel startup
// and published via one legacy sense-reversing barrier.
// ---------------------------------------------------------------------------

typedef __bf16 bf16;
typedef __attribute__((ext_vector_type(8))) __bf16 bf16x8;
typedef __attribute__((ext_vector_type(4))) float f32x4;
typedef unsigned int uint;

#define MFMA(a, b, c) __builtin_amdgcn_mfma_f32_16x16x32_bf16((a), (b), (c), 0, 0, 0)

// ---- workspace byte offsets (all 256-aligned) ----
#define O_X1     0UL          // X1pre bf16 [200][64][2048]          52,428,800
#define O_EMBB   52428800UL   // emb bf16 [8000][512]                 8,192,000
#define O_WEMBP  60620800UL   // Wih1 embed-part, permuted rows, bf16 [2048][512]
#define O_WZ1    62717952UL   // [Wih1_ctx | Whh1] permuted, bf16 [2048][640]
#define O_WZ2    65339392UL   // [Whh2 | Wih2] permuted, bf16 [512][640]
#define O_B1P    65994752UL   // b_ih1+b_hh1 permuted fp32 [2048]
#define O_B2P    66002944UL   // b_ih2+b_hh2 permuted fp32 [512]
#define O_WOUTB  66004992UL   // W_out bf16 [8000][256]
#define O_KEYB   70100992UL   // key bf16 [500][64][128]
#define O_VALB   78292992UL   // values bf16 [500][64][128]
#define O_H1     86484992UL   // h1 state bf16 [2][64][512]
#define O_H2     86616064UL   // h2 state bf16 [2][64][128]
#define O_PART   86648832UL   // attn partials [64][4][272B]: m,s fp32 + 128 bf16
#define O_H2CTX  86718464UL   // [h2|ctx] bf16 [200][64][256]
#define O_BAR    93272064UL   // legacy barrier: cnt at [0], gen at [16] (uints)

// ---- loop kernel LDS offsets ----
#define LO_WA   0        // A-weight slice: 16 rows x 640, pitch 648 halves (20736B)
#define LO_WB   20736    // B-weight slice: 32 rows x 640, pitch 648 (41472B)
#define LO_KEY  62208    // key chunk: 125 x 128, pitch 132 halves (33000B)
#define LO_VAL  95232    // val chunk: same
#define LO_CTX  128240   // ctx stage: 32 x 128, pitch 136 halves (8704B)
#define LO_ZS   136944   // z scratch: [4 waves][32 m][33] fp32 (16896B)
#define LO_C1   153840   // c1 slice [32][4] fp32
#define LO_C2   154352   // c2 slice [32][8] fp32
#define LO_EL   155376   // energies [128] fp32
#define LO_PL   155888   // probs [128] fp32
#define LO_H2F  156400   // h2 row [128] fp32
#define LO_RED  156912   // reduction scratch
#define LDS_TOTAL 156944

// fast barrier layout inside d_out (dead scratch during loop_kernel):
//   flag[bid] at u32 index bid*64 (256B stride), gen at u32 index 16384
#define FLAG_STRIDE 64
#define GEN_IDX     16384

__device__ inline float sigf(float x) { return 1.f / (1.f + __expf(-x)); }
__device__ inline float tanhf_(float x) { float e = __expf(2.f * x); return 1.f - 2.f / (e + 1.f); }
__device__ inline float bflo(uint u) { union { uint u; float f; } c; c.u = u << 16; return c.f; }
__device__ inline float bfhi(uint u) { union { uint u; float f; } c; c.u = u & 0xffff0000u; return c.f; }
__device__ inline float wred_max(float v) {
#pragma unroll
  for (int m = 32; m; m >>= 1) v = fmaxf(v, __shfl_xor(v, m, 64));
  return v;
}
__device__ inline float wred_sum(float v) {
#pragma unroll
  for (int m = 32; m; m >>= 1) v += __shfl_xor(v, m, 64);
  return v;
}

// legacy sense-reversing grid barrier (contended single counter). Stale-safe
// across rocprof replays; used ONCE at startup to publish zeroed fast flags.
__device__ inline void gbar_slow(uint* bar) {
  __syncthreads();
  if (threadIdx.x == 0) {
    __threadfence();
    uint g = __hip_atomic_load(bar + 16, __ATOMIC_RELAXED, __HIP_MEMORY_SCOPE_AGENT);
    uint a = __hip_atomic_fetch_add(bar + 0, 1u, __ATOMIC_ACQ_REL, __HIP_MEMORY_SCOPE_AGENT);
    if (a == 255u) {
      __hip_atomic_store(bar + 0, 0u, __ATOMIC_RELAXED, __HIP_MEMORY_SCOPE_AGENT);
      __hip_atomic_fetch_add(bar + 16, 1u, __ATOMIC_RELEASE, __HIP_MEMORY_SCOPE_AGENT);
    } else {
      int spins = 0;
      while (__hip_atomic_load(bar + 16, __ATOMIC_ACQUIRE, __HIP_MEMORY_SCOPE_AGENT) == g) {
        __builtin_amdgcn_s_sleep(1);
        if (++spins > (1 << 18)) break;  // failsafe: never hang the bench
      }
    }
    __threadfence();
  }
  __syncthreads();
}

// fast flag-array grid barrier. Arrival: one release-store per WG to its own
// 256B-strided line (fully parallel, no RMW). Detection: WG0's 256 threads
// poll one flag each, then thread 0 releases gen; other WG leaders poll gen.
// Epochs are monotonically increasing; no reset needed within a run.
__device__ inline void gbar_fast(uint* __restrict__ flags, uint ep, int bid, int tid) {
  __syncthreads();
  if (bid == 0) {
    if (tid == 0) {
      __threadfence();
      __hip_atomic_store(flags, ep, __ATOMIC_RELEASE, __HIP_MEMORY_SCOPE_AGENT);
    }
    int spins = 0;
    while (__hip_atomic_load(flags + tid * FLAG_STRIDE, __ATOMIC_ACQUIRE,
                             __HIP_MEMORY_SCOPE_AGENT) < ep) {
      __builtin_amdgcn_s_sleep(1);
      if (++spins > (1 << 18)) break;  // failsafe: never hang the bench
    }
    __syncthreads();  // all 256 flags acquired -> all WGs' writes visible blockwide
    if (tid == 0) {
      __hip_atomic_store(flags + GEN_IDX, ep, __ATOMIC_RELEASE, __HIP_MEMORY_SCOPE_AGENT);
    }
  } else {
    if (tid == 0) {
      __threadfence();
      __hip_atomic_store(flags + bid * FLAG_STRIDE, ep, __ATOMIC_RELEASE,
                         __HIP_MEMORY_SCOPE_AGENT);
      int spins = 0;
      while (__hip_atomic_load(flags + GEN_IDX, __ATOMIC_ACQUIRE,
                               __HIP_MEMORY_SCOPE_AGENT) < ep) {
        __builtin_amdgcn_s_sleep(1);
        if (++spins > (1 << 18)) break;  // failsafe
      }
      __threadfence();
    }
    __syncthreads();
  }
}

// =============================== prep ======================================
__global__ __launch_bounds__(256) void prep_kernel(
    const float* __restrict__ key, const float* __restrict__ values,
    const float* __restrict__ emb, const float* __restrict__ Wih1,
    const float* __restrict__ Whh1, const float* __restrict__ bih1,
    const float* __restrict__ bhh1, const float* __restrict__ Wih2,
    const float* __restrict__ Whh2, const float* __restrict__ bih2,
    const float* __restrict__ bhh2, const float* __restrict__ Wout,
    char* __restrict__ ws) {
  long g = (long)blockIdx.x * 256 + threadIdx.x;
  long str = (long)gridDim.x * 256;
  bf16* embB = (bf16*)(ws + O_EMBB);
  bf16* WembP = (bf16*)(ws + O_WEMBP);
  bf16* Wz1p = (bf16*)(ws + O_WZ1);
  bf16* Wz2p = (bf16*)(ws + O_WZ2);
  float* b1p = (float*)(ws + O_B1P);
  float* b2p = (float*)(ws + O_B2P);
  bf16* WoutB = (bf16*)(ws + O_WOUTB);
  bf16* keyB = (bf16*)(ws + O_KEYB);
  bf16* valB = (bf16*)(ws + O_VALB);

  for (long i = g; i < 8000L * 512; i += str) embB[i] = (bf16)emb[i];
  for (long i = g; i < 2048L * 512; i += str) {
    long gg = i >> 9, k = i & 511;
    long pg = (gg & 3) * 512 + (gg >> 2);
    WembP[i] = (bf16)Wih1[pg * 640 + k];
  }
  for (long i = g; i < 2048L * 640; i += str) {
    long gg = i / 640, k = i - gg * 640;
    long pg = (gg & 3) * 512 + (gg >> 2);
    float v = (k < 128) ? Wih1[pg * 640 + 512 + k] : Whh1[pg * 512 + (k - 128)];
    Wz1p[i] = (bf16)v;
  }
  for (long i = g; i < 512L * 640; i += str) {
    long gg = i / 640, k = i - gg * 640;
    long pg = (gg & 3) * 128 + (gg >> 2);
    float v = (k < 128) ? Whh2[pg * 128 + k] : Wih2[pg * 512 + (k - 128)];
    Wz2p[i] = (bf16)v;
  }
  for (long i = g; i < 2048; i += str) {
    long pg = (i & 3) * 512 + (i >> 2);
    b1p[i] = bih1[pg] + bhh1[pg];
  }
  for (long i = g; i < 512; i += str) {
    long pg = (i & 3) * 128 + (i >> 2);
    b2p[i] = bih2[pg] + bhh2[pg];
  }
  for (long i = g; i < 8000L * 256; i += str) WoutB[i] = (bf16)Wout[i];
  for (long i = g; i < 500L * 64 * 128; i += str) {
    keyB[i] = (bf16)key[i];
    valB[i] = (bf16)values[i];
  }
  // zero h1/h2 state (163840 B) and legacy barrier (256 B)
  uint* z = (uint*)(ws + O_H1);
  for (long i = g; i < 40960; i += str) z[i] = 0u;
  uint* bz = (uint*)(ws + O_BAR);
  for (long i = g; i < 64; i += str) bz[i] = 0u;
}

// ========================= K1: embedding pre-GEMM ==========================
// X1pre[m=t*64+n][g~] = sum_k emb[text[n][t]][k] * WembP[g~][k] + b1p[g~]
__global__ __launch_bounds__(256) void k1_gemm(const int* __restrict__ text,
                                               char* __restrict__ ws) {
  const int tid = threadIdx.x, lane = tid & 63, wave = tid >> 6;
  const int l15 = lane & 15, quad = lane >> 4;
  const int Nb = blockIdx.x, Mb = blockIdx.y;  // 32 x 200
  const bf16* embB = (const bf16*)(ws + O_EMBB);
  const bf16* WembP = (const bf16*)(ws + O_WEMBP);
  const float* b1p = (const float*)(ws + O_B1P);
  bf16* X1 = (bf16*)(ws + O_X1);

  int m = Mb * 64 + wave * 16 + l15;
  int tcol = m >> 6, n = m & 63;
  int vid = text[n * 200 + tcol];  // row 0 of emb is all-zero (padding)
  const bf16* arow = embB + (size_t)vid * 512 + quad * 8;

  f32x4 acc[4];
#pragma unroll
  for (int nt = 0; nt < 4; ++nt) {
    float b = b1p[Nb * 64 + nt * 16 + l15];
    acc[nt] = (f32x4){b, b, b, b};
  }
  for (int kt = 0; kt < 16; ++kt) {
    bf16x8 af = *(const bf16x8*)(arow + kt * 32);
#pragma unroll
    for (int nt = 0; nt < 4; ++nt) {
      bf16x8 bfr = *(const bf16x8*)(WembP + (size_t)(Nb * 64 + nt * 16 + l15) * 512 +
                                    kt * 32 + quad * 8);
      acc[nt] = MFMA(af, bfr, acc[nt]);
    }
  }
#pragma unroll
  for (int nt = 0; nt < 4; ++nt)
#pragma unroll
    for (int r = 0; r < 4; ++r) {
      int mr = Mb * 64 + wave * 16 + quad * 4 + r;
      X1[(size_t)mr * 2048 + Nb * 64 + nt * 16 + l15] = (bf16)acc[nt][r];
    }
}

// ===================== persistent recurrent loop kernel ====================
__device__ inline void combine_ctx(int t, int nA0, int ga, int tid,
                                   char* __restrict__ smem, const char* __restrict__ part,
                                   bf16* __restrict__ h2ctx, bool wlds) {
  int m = tid >> 3, kk = tid & 7;
  const char* pb = part + (size_t)(nA0 + m) * 4 * 272;
  float mc0 = ((const float*)(pb))[0], sc0 = ((const float*)(pb))[1];
  float mc1 = ((const float*)(pb + 272))[0], sc1 = ((const float*)(pb + 272))[1];
  float mc2 = ((const float*)(pb + 544))[0], sc2 = ((const float*)(pb + 544))[1];
  float mc3 = ((const float*)(pb + 816))[0], sc3 = ((const float*)(pb + 816))[1];
  float M = fmaxf(fmaxf(mc0, mc1), fmaxf(mc2, mc3));
  float w0 = __expf(mc0 - M), w1 = __expf(mc1 - M);
  float w2 = __expf(mc2 - M), w3 = __expf(mc3 - M);
  float S = sc0 * w0 + sc1 * w1 + sc2 * w2 + sc3 * w3;
  float inv = 1.f / S;
  const bf16* x0 = (const bf16*)(pb + 8);
  const bf16* x1 = (const bf16*)(pb + 280);
  const bf16* x2 = (const bf16*)(pb + 552);
  const bf16* x3 = (const bf16*)(pb + 824);
  bf16* ctxL = (bf16*)(smem + LO_CTX) + m * 136;
#pragma unroll
  for (int i = 0; i < 16; ++i) {
    int k = kk * 16 + i;
    float v = w0 * (float)x0[k] + w1 * (float)x1[k] + w2 * (float)x2[k] + w3 * (float)x3[k];
    bf16 hv = (bf16)(v * inv);
    if (wlds) ctxL[k] = hv;
    if (ga == 0) h2ctx[(size_t)((t - 1) * 64 + nA0 + m) * 256 + 128 + k] = hv;
  }
}

__global__ __launch_bounds__(256, 1) void loop_kernel(const float* __restrict__ values,
                                                      const int* __restrict__ lens,
                                                      uint* __restrict__ gflags,
                                                      char* __restrict__ ws) {
  extern __shared__ __align__(16) char smem[];
  const int bid = blockIdx.x, tid = threadIdx.x;
  const int lane = tid & 63, wave = tid >> 6;
  const int l15 = lane & 15, quad = lane >> 4;

  // roles
  const int ra = bid & 1, ga = bid >> 1;  // A: 2 rowgrps x 128 gategrps (16 z~ rows)
  const int nA0 = 32 * ra;
  const int isB = (bid < 32);
  const int hb = bid >> 1;                 // B: 2 rowgrps x 16 h2grps (32 z~ rows)
  const int nB0 = 32 * (bid & 1);
  const int nc = bid >> 2, cc = bid & 3;   // C: 64 rows x 4 T-chunks of 125

  bf16* X1 = (bf16*)(ws + O_X1);
  const bf16* Wz1p = (const bf16*)(ws + O_WZ1);
  const bf16* Wz2p = (const bf16*)(ws + O_WZ2);
  const float* b2p = (const float*)(ws + O_B2P);
  const bf16* keyB = (const bf16*)(ws + O_KEYB);
  const bf16* valB = (const bf16*)(ws + O_VALB);
  bf16* h1b = (bf16*)(ws + O_H1);    // [2][64][512]
  bf16* h2b = (bf16*)(ws + O_H2);    // [2][64][128]
  char* part = ws + O_PART;          // [64][4][272]
  bf16* h2ctx = (bf16*)(ws + O_H2CTX);
  uint* bar = (uint*)(ws + O_BAR);

  // zero this WG's fast-barrier flag (and gen) before publishing via the
  // legacy barrier below — makes the kernel replay-safe without prep.
  if (tid == 0) {
    __hip_atomic_store(gflags + bid * FLAG_STRIDE, 0u, __ATOMIC_RELAXED,
                       __HIP_MEMORY_SCOPE_AGENT);
    if (bid == 0)
      __hip_atomic_store(gflags + GEN_IDX, 0u, __ATOMIC_RELAXED, __HIP_MEMORY_SCOPE_AGENT);
  }

  // ---- prologue: stage persistent LDS ----
  for (int i = tid; i < 16 * 80; i += 256) {  // A weights: 16 rows x 1280B
    int r = i / 80, c = i % 80;
    *(uint4*)(smem + LO_WA + r * 1296 + c * 16) =
        *(const uint4*)((const char*)Wz1p + (size_t)(16 * ga + r) * 1280 + c * 16);
  }
  if (isB) {
    for (int i = tid; i < 32 * 80; i += 256) {
      int r = i / 80, c = i % 80;
      *(uint4*)(smem + LO_WB + r * 1296 + c * 16) =
          *(const uint4*)((const char*)Wz2p + (size_t)(32 * hb + r) * 1280 + c * 16);
    }
  }
  for (int i = tid; i < 125 * 32; i += 256) {  // KV chunk: 125 rows x 256B
    int r = i >> 5, c = i & 31;
    size_t src = ((size_t)(cc * 125 + r) * 64 + nc) * 256 + c * 8;
    *(uint2*)(smem + LO_KEY + r * 264 + c * 8) = *(const uint2*)((const char*)keyB + src);
    *(uint2*)(smem + LO_VAL + r * 264 + c * 8) = *(const uint2*)((const char*)valB + src);
  }
  float* c1s = (float*)(smem + LO_C1);
  float* c2s = (float*)(smem + LO_C2);
  if (tid < 128) c1s[tid] = 0.f;
  c2s[tid] = 0.f;
  float* eL = (float*)(smem + LO_EL);
  float* pL = (float*)(smem + LO_PL);
  float* h2f = (float*)(smem + LO_H2F);
  float* red = (float*)(smem + LO_RED);
  const int lenr = lens[nc];
  __syncthreads();

  // startup fence: publishes the zeroed fast flags to all WGs (slow, once)
  gbar_slow(bar);
  uint ep = 0;

  for (int t = 0; t < 200; ++t) {
    const int p = t & 1;
    // ================= PHASE A =================
    // ctx(t-1) into LDS (combine attention partials; t==0 uses values[0])
    if (t == 0) {
      int m = tid >> 3, kk = tid & 7;
      bf16* ctxL = (bf16*)(smem + LO_CTX) + m * 136;
#pragma unroll
      for (int i = 0; i < 16; ++i) {
        int k = kk * 16 + i;
        ctxL[k] = (bf16)values[(nA0 + m) * 128 + k];
      }
    } else {
      combine_ctx(t, nA0, ga, tid, smem, part, h2ctx, true);
    }
    __syncthreads();
    // z1 = X1pre + [ctx | h1prev] @ slice(Wz1p)^T  (K split over 4 waves)
    {
      f32x4 acc0 = {0, 0, 0, 0}, acc1 = {0, 0, 0, 0};
      const bf16* h1p = h1b + p * 32768;
#pragma unroll
      for (int q = 0; q < 5; ++q) {
        int kt = wave * 5 + q;
        bf16x8 bfr = *(const bf16x8*)(smem + LO_WA + l15 * 1296 + (kt * 32 + quad * 8) * 2);
        bf16x8 a0, a1;
        if (kt < 4) {
          a0 = *(const bf16x8*)(smem + LO_CTX + l15 * 272 + (kt * 32 + quad * 8) * 2);
          a1 = *(const bf16x8*)(smem + LO_CTX + (16 + l15) * 272 + (kt * 32 + quad * 8) * 2);
        } else {
          const bf16* base = h1p + (kt - 4) * 32 + quad * 8;
          a0 = *(const bf16x8*)(base + (size_t)(nA0 + l15) * 512);
          a1 = *(const bf16x8*)(base + (size_t)(nA0 + 16 + l15) * 512);
        }
        acc0 = MFMA(a0, bfr, acc0);
        acc1 = MFMA(a1, bfr, acc1);
      }
      float* zs = (float*)(smem + LO_ZS) + wave * 1056;
#pragma unroll
      for (int r = 0; r < 4; ++r) {
        zs[(quad * 4 + r) * 33 + l15] = acc0[r];
        zs[(16 + quad * 4 + r) * 33 + l15] = acc1[r];
      }
    }
    __syncthreads();
    // gating -> h1(t), c1
    if (tid < 128) {
      int m = tid >> 2, j = tid & 3;
      float zi = 0, zf = 0, zg = 0, zo = 0;
      const float* zr = (const float*)(smem + LO_ZS);
#pragma unroll
      for (int w = 0; w < 4; ++w) {
        const float* q_ = zr + w * 1056 + m * 33 + 4 * j;
        zi += q_[0]; zf += q_[1]; zg += q_[2]; zo += q_[3];
      }
      const bf16* xp = X1 + (size_t)(t * 64 + nA0 + m) * 2048 + ga * 16 + 4 * j;
      zi += (float)xp[0]; zf += (float)xp[1]; zg += (float)xp[2]; zo += (float)xp[3];
      float c = sigf(zf) * c1s[tid] + sigf(zi) * tanhf_(zg);
      float h = sigf(zo) * tanhf_(c);
      c1s[tid] = c;
      h1b[(p ^ 1) * 32768 + (size_t)(nA0 + m) * 512 + ga * 4 + j] = (bf16)h;
    }
    gbar_fast(gflags, ++ep, bid, tid);
    // ================= PHASE B =================
    if (isB) {
      f32x4 a00 = {0, 0, 0, 0}, a01 = {0, 0, 0, 0}, a10 = {0, 0, 0, 0}, a11 = {0, 0, 0, 0};
      const bf16* h2p = h2b + p * 8192;
      const bf16* h1n = h1b + (p ^ 1) * 32768;
#pragma unroll
      for (int q = 0; q < 5; ++q) {
        int kt = wave * 5 + q;
        bf16x8 b0 = *(const bf16x8*)(smem + LO_WB + l15 * 1296 + (kt * 32 + quad * 8) * 2);
        bf16x8 b1 = *(const bf16x8*)(smem + LO_WB + (16 + l15) * 1296 + (kt * 32 + quad * 8) * 2);
        bf16x8 a0, a1;
        if (kt < 4) {
          const bf16* base = h2p + kt * 32 + quad * 8;
          a0 = *(const bf16x8*)(base + (size_t)(nB0 + l15) * 128);
          a1 = *(const bf16x8*)(base + (size_t)(nB0 + 16 + l15) * 128);
        } else {
          const bf16* base = h1n + (kt - 4) * 32 + quad * 8;
          a0 = *(const bf16x8*)(base + (size_t)(nB0 + l15) * 512);
          a1 = *(const bf16x8*)(base + (size_t)(nB0 + 16 + l15) * 512);
        }
        a00 = MFMA(a0, b0, a00); a01 = MFMA(a0, b1, a01);
        a10 = MFMA(a1, b0, a10); a11 = MFMA(a1, b1, a11);
      }
      float* zs = (float*)(smem + LO_ZS) + wave * 1056;
#pragma unroll
      for (int r = 0; r < 4; ++r) {
        zs[(quad * 4 + r) * 33 + l15] = a00[r];
        zs[(quad * 4 + r) * 33 + 16 + l15] = a01[r];
        zs[(16 + quad * 4 + r) * 33 + l15] = a10[r];
        zs[(16 + quad * 4 + r) * 33 + 16 + l15] = a11[r];
      }
      __syncthreads();
      {
        int m = tid >> 3, jj = tid & 7;
        float zi = 0, zf = 0, zg = 0, zo = 0;
        const float* zr = (const float*)(smem + LO_ZS);
#pragma unroll
        for (int w = 0; w < 4; ++w) {
          const float* q_ = zr + w * 1056 + m * 33 + 4 * jj;
          zi += q_[0]; zf += q_[1]; zg += q_[2]; zo += q_[3];
        }
        const float* bb = b2p + 32 * hb + 4 * jj;
        zi += bb[0]; zf += bb[1]; zg += bb[2]; zo += bb[3];
        float c = sigf(zf) * c2s[tid] + sigf(zi) * tanhf_(zg);
        float h = sigf(zo) * tanhf_(c);
        c2s[tid] = c;
        bf16 hv = (bf16)h;
        h2b[(p ^ 1) * 8192 + (size_t)(nB0 + m) * 128 + 8 * hb + jj] = hv;
        h2ctx[(size_t)(t * 64 + nB0 + m) * 256 + 8 * hb + jj] = hv;
      }
    }
    gbar_fast(gflags, ++ep, bid, tid);
    // ================= PHASE C =================
    if (tid < 128) h2f[tid] = (float)h2b[(p ^ 1) * 8192 + (size_t)nc * 128 + tid];
    __syncthreads();
    if (tid < 125) {
      int gt = cc * 125 + tid;
      float e = -1e30f;
      if (gt < lenr) {
        const uint* kr = (const uint*)(smem + LO_KEY + tid * 264);
        float s = 0.f;
#pragma unroll 8
        for (int k2 = 0; k2 < 64; ++k2) {
          uint u = kr[k2];
          s += h2f[2 * k2] * bflo(u) + h2f[2 * k2 + 1] * bfhi(u);
        }
        e = s;
      }
      eL[tid] = e;
    } else if (tid < 128) {
      eL[tid] = -1e30f;
    }
    __syncthreads();
    if (tid < 64) {
      float v = fmaxf(eL[tid], eL[tid + 64]);
      v = wred_max(v);
      if (tid == 0) red[0] = v;
    }
    __syncthreads();
    float mC = red[0];
    if (tid < 128) {
      float pv = 0.f;
      if (tid < 125 && (cc * 125 + tid) < lenr) pv = __expf(eL[tid] - mC);
      pL[tid] = pv;
    }
    __syncthreads();
    if (tid < 64) {
      float v = pL[tid] + pL[tid + 64];
      v = wred_sum(v);
      if (tid == 0) red[1] = v;
    }
    __syncthreads();
    {
      char* pbase = part + (size_t)(nc * 4 + cc) * 272;
      if (tid == 0) {
        ((float*)pbase)[0] = mC;
        ((float*)pbase)[1] = red[1];
      }
      if (tid < 64) {
        const char* vbase = smem + LO_VAL + tid * 4;
        float a0 = 0.f, a1 = 0.f;
        for (int tt = 0; tt < 125; ++tt) {
          float pv = pL[tt];
          uint u = *(const uint*)(vbase + tt * 264);
          a0 += pv * bflo(u);
          a1 += pv * bfhi(u);
        }
        bf16* dst = (bf16*)(pbase + 8);
        dst[2 * tid] = (bf16)a0;
        dst[2 * tid + 1] = (bf16)a1;
      }
    }
    gbar_fast(gflags, ++ep, bid, tid);
  }
  // epilogue: finalize ctx(199) into h2ctx
  if (ga == 0) combine_ctx(200, nA0, ga, tid, smem, part, h2ctx, false);
}

// ========================= K4: output projection ===========================
__global__ __launch_bounds__(256) void k4_gemm(const float* __restrict__ bout,
                                               float* __restrict__ out,
                                               char* __restrict__ ws) {
  const int tid = threadIdx.x, lane = tid & 63, wave = tid >> 6;
  const int l15 = lane & 15, quad = lane >> 4;
  const int Nb = blockIdx.x, Mb = blockIdx.y;  // 63 x 200
  const bf16* A = (const bf16*)(ws + O_H2CTX);
  const bf16* B = (const bf16*)(ws + O_WOUTB);

  int mrow = Mb * 64 + wave * 16 + l15;
  const bf16* arow = A + (size_t)mrow * 256 + quad * 8;

  int vs[8];
  f32x4 acc[8];
#pragma unroll
  for (int nt = 0; nt < 8; ++nt) {
    int v = Nb * 128 + nt * 16 + l15;
    vs[nt] = v < 8000 ? v : 7999;
    float b = (v < 8000) ? bout[v] : 0.f;
    acc[nt] = (f32x4){b, b, b, b};
  }
#pragma unroll
  for (int kt = 0; kt < 8; ++kt) {
    bf16x8 af = *(const bf16x8*)(arow + kt * 32);
#pragma unroll
    for (int nt = 0; nt < 8; ++nt) {
      bf16x8 bfr = *(const bf16x8*)(B + (size_t)vs[nt] * 256 + kt * 32 + quad * 8);
      acc[nt] = MFMA(af, bfr, acc[nt]);
    }
  }
#pragma unroll
  for (int nt = 0; nt < 8; ++nt) {
    int v = Nb * 128 + nt * 16 + l15;
    if (v < 8000) {
#pragma unroll
      for (int r = 0; r < 4; ++r) {
        int mr = Mb * 64 + wave * 16 + quad * 4 + r;
        int n = mr & 63, tt = mr >> 6;
        out[(size_t)(n * 200 + tt) * 8000 + v] = acc[nt][r];
      }
    }
  }
}

// ================================ launch ===================================
extern "C" void kernel_launch(void* const* d_in, const int* in_sizes, int n_in,
                              void* d_out, int out_size, void* d_ws, size_t ws_size,
                              hipStream_t stream) {
  const float* key = (const float*)d_in[0];
  const float* values = (const float*)d_in[1];
  const int* lens = (const int*)d_in[2];
  const int* text = (const int*)d_in[3];
  const float* emb = (const float*)d_in[4];
  const float* Wih1 = (const float*)d_in[5];
  const float* Whh1 = (const float*)d_in[6];
  const float* bih1 = (const float*)d_in[7];
  const float* bhh1 = (const float*)d_in[8];
  const float* Wih2 = (const float*)d_in[9];
  const float* Whh2 = (const float*)d_in[10];
  const float* bih2 = (const float*)d_in[11];
  const float* bhh2 = (const float*)d_in[12];
  const float* Wout = (const float*)d_in[13];
  const float* bout = (const float*)d_in[14];
  float* out = (float*)d_out;
  char* ws = (char*)d_ws;

  // allow >64KB dynamic LDS for the persistent kernel (idempotent)
  hipFuncSetAttribute(reinterpret_cast<const void*>(loop_kernel),
                      hipFuncAttributeMaxDynamicSharedMemorySize, 160 * 1024);

  prep_kernel<<<1024, 256, 0, stream>>>(key, values, emb, Wih1, Whh1, bih1, bhh1,
                                        Wih2, Whh2, bih2, bhh2, Wout, ws);
  k1_gemm<<<dim3(32, 200), 256, 0, stream>>>(text, ws);
  // fast-barrier flags live at the front of d_out: dead scratch during the
  // loop, fully overwritten by k4_gemm afterwards.
  loop_kernel<<<256, 256, LDS_TOTAL, stream>>>(values, lens, (uint*)out, ws);
  k4_gemm<<<dim3(63, 200), 256, 0, stream>>>(bout, out, ws);
}